// Round 7
// baseline (365.301 us; speedup 1.0000x reference)
//
#include <hip/hip_runtime.h>
#include <hip/hip_bf16.h>

// DirectionalPropagation1D fused v7: B=16, C=64, H=256, W=256, N=4096 seqs.
// v7 = v5 geometry (256 blocks, 16 seq/block, 1 block/CU, 128 KB LDS) with
// EIGHT waves: wave 0 = recurrence (register state, permuted-Ws trick,
// unchanged from v5); waves 1-4 = feat stagers (8 c-pairs each -> 2x the
// memory-carrying waves, half the loads per wave); waves 5-7 = out drainers.
// Tests/fixes the per-CU memory-parallelism wall (R2-R6 post-mortem).
// One lgkm-only barrier per 16-step chunk (17 total), all 8 waves.

typedef __attribute__((ext_vector_type(8))) short short8;
typedef __attribute__((ext_vector_type(4))) short short4v;
typedef __attribute__((ext_vector_type(2))) short short2v;
typedef __attribute__((ext_vector_type(4))) float f32x4;

union FragU { unsigned int u[4]; short8 v; };
union PkU { unsigned int u; short2v s2; };

__device__ __forceinline__ unsigned int pk2(float a, float b) {
    unsigned short lo = __bfloat16_as_ushort(__float2bfloat16(a));
    unsigned short hi = __bfloat16_as_ushort(__float2bfloat16(b));
    return (unsigned int)lo | ((unsigned int)hi << 16);
}
__device__ __forceinline__ float b2f(short x) {
    return __uint_as_float(((unsigned int)(unsigned short)x) << 16);
}

// feat staging [w16][n16][c64] bf16, XOR-swizzled (same function both sides).
__device__ __forceinline__ int fsi(int w, int n, int c) {
    return (w * 1024 + n * 64 + c) ^ ((n & 7) << 3);
}
// out staging [o64][n16][w16] bf16, XOR-swizzled (same function both sides).
__device__ __forceinline__ int ogi(int o, int n, int w) {
    return (o * 256 + n * 16 + w) ^ ((((o >> 2) ^ (n >> 2)) & 3) << 2);
}

// LDS-only barrier: global traffic stays in flight across it.
#define BAR() asm volatile("s_waitcnt lgkmcnt(0)\n\ts_barrier" ::: "memory")

template<int V> struct Ic { static constexpr int value = V; };

__global__ __launch_bounds__(512, 1) void dp_v7_kernel(
    const float* __restrict__ feat, const float* __restrict__ conf,
    const float* __restrict__ Wi, const float* __restrict__ bi,
    const float* __restrict__ Ws, const float* __restrict__ bs,
    const float* __restrict__ bias, float* __restrict__ outp)
{
    __shared__ unsigned short fs[2][16384];  // 64 KB feat bf16, ping-pong
    __shared__ unsigned short og[2][16384];  // 64 KB out bf16, ping-pong

    const int tid = threadIdx.x;
    const int lane = tid & 63;
    const int wid = tid >> 6;                // 0..7
    const int l15 = lane & 15, g4 = lane >> 4;
    const int nb = blockIdx.x;
    const int b = nb >> 4, h0 = (nb & 15) * 16;

    const float* fb = feat + (size_t)b * 64 * 65536 + (size_t)h0 * 256;

    if (wid == 0) {
        // ================= recurrence wave (identical to v5) =================
        const float* gb = conf + ((size_t)(b * 256) + h0 + l15) * 256;

        FragU Ai[4][2], As[4][2];
        #pragma unroll
        for (int t = 0; t < 4; ++t)
            #pragma unroll
            for (int h = 0; h < 2; ++h) {
                const float* si = Wi + (16 * t + l15) * 64 + 32 * h + g4 * 8;
                const float* ss = Ws + (16 * t + l15) * 64;
                #pragma unroll
                for (int d = 0; d < 4; ++d) {
                    Ai[t][h].u[d] = pk2(si[2 * d], si[2 * d + 1]);
                    const int c0 = 16 * (2 * h + (d >> 1)) + 4 * g4 + 2 * (d & 1);
                    As[t][h].u[d] = pk2(ss[c0], ss[c0 + 1]);
                }
            }
        f32x4 binit[4];
        #pragma unroll
        for (int t = 0; t < 4; ++t)
            #pragma unroll
            for (int r = 0; r < 4; ++r) {
                int o = 16 * t + 4 * g4 + r;
                binit[t][r] = bi[o] + bs[o] + bias[o];
            }

        f32x4 gqA[4], gqB[4];
        #pragma unroll
        for (int q = 0; q < 4; ++q) gqA[q] = *(const f32x4*)(gb + 4 * q);

        FragU S0, S1;
        #pragma unroll
        for (int d = 0; d < 4; ++d) { S0.u[d] = 0u; S1.u[d] = 0u; }

        float curE[4][4];

        BAR();  // matches producers' post-prologue barrier

        auto run_chunk = [&](auto pc, int cc) {
            constexpr int P = decltype(pc)::value;
            f32x4 (&gqc)[4] = P ? gqB : gqA;
            f32x4 (&gqn)[4] = P ? gqA : gqB;
            const int w0 = cc * 16;
            #pragma unroll
            for (int u = 0; u < 16; ++u) {
                short8 F0 = *(const short8*)&fs[P][fsi(u, l15, 8 * g4)];
                short8 F1 = *(const short8*)&fs[P][fsi(u, l15, 32 + 8 * g4)];

                if (u == 2 && cc < 15) {
                    #pragma unroll
                    for (int q = 0; q < 4; ++q)
                        gqn[q] = *(const f32x4*)(gb + w0 + 16 + 4 * q);
                }

                f32x4 a0 = binit[0], a1 = binit[1], a2 = binit[2], a3 = binit[3];
                a0 = __builtin_amdgcn_mfma_f32_16x16x32_bf16(Ai[0][0].v, F0, a0, 0, 0, 0);
                a1 = __builtin_amdgcn_mfma_f32_16x16x32_bf16(Ai[1][0].v, F0, a1, 0, 0, 0);
                a2 = __builtin_amdgcn_mfma_f32_16x16x32_bf16(Ai[2][0].v, F0, a2, 0, 0, 0);
                a3 = __builtin_amdgcn_mfma_f32_16x16x32_bf16(Ai[3][0].v, F0, a3, 0, 0, 0);
                a0 = __builtin_amdgcn_mfma_f32_16x16x32_bf16(Ai[0][1].v, F1, a0, 0, 0, 0);
                a1 = __builtin_amdgcn_mfma_f32_16x16x32_bf16(Ai[1][1].v, F1, a1, 0, 0, 0);
                a2 = __builtin_amdgcn_mfma_f32_16x16x32_bf16(Ai[2][1].v, F1, a2, 0, 0, 0);
                a3 = __builtin_amdgcn_mfma_f32_16x16x32_bf16(Ai[3][1].v, F1, a3, 0, 0, 0);
                a0 = __builtin_amdgcn_mfma_f32_16x16x32_bf16(As[0][0].v, S0.v, a0, 0, 0, 0);
                a1 = __builtin_amdgcn_mfma_f32_16x16x32_bf16(As[1][0].v, S0.v, a1, 0, 0, 0);
                a2 = __builtin_amdgcn_mfma_f32_16x16x32_bf16(As[2][0].v, S0.v, a2, 0, 0, 0);
                a3 = __builtin_amdgcn_mfma_f32_16x16x32_bf16(As[3][0].v, S0.v, a3, 0, 0, 0);
                a0 = __builtin_amdgcn_mfma_f32_16x16x32_bf16(As[0][1].v, S1.v, a0, 0, 0, 0);
                a1 = __builtin_amdgcn_mfma_f32_16x16x32_bf16(As[1][1].v, S1.v, a1, 0, 0, 0);
                a2 = __builtin_amdgcn_mfma_f32_16x16x32_bf16(As[2][1].v, S1.v, a2, 0, 0, 0);
                a3 = __builtin_amdgcn_mfma_f32_16x16x32_bf16(As[3][1].v, S1.v, a3, 0, 0, 0);

                float cur[4][4];
                #pragma unroll
                for (int r = 0; r < 4; ++r) {
                    cur[0][r] = fmaxf(a0[r], 0.f);
                    cur[1][r] = fmaxf(a1[r], 0.f);
                    cur[2][r] = fmaxf(a2[r], 0.f);
                    cur[3][r] = fmaxf(a3[r], 0.f);
                }

                // out staging: pack w-pairs, 16 b32 DS writes on odd steps.
                if ((u & 1) == 0) {
                    #pragma unroll
                    for (int t = 0; t < 4; ++t)
                        #pragma unroll
                        for (int r = 0; r < 4; ++r) curE[t][r] = cur[t][r];
                } else {
                    #pragma unroll
                    for (int t = 0; t < 4; ++t)
                        #pragma unroll
                        for (int r = 0; r < 4; ++r) {
                            PkU pk; pk.u = pk2(curE[t][r], cur[t][r]);
                            *(short2v*)&og[P][ogi(16 * t + 4 * g4 + r, l15, u - 1)] = pk.s2;
                        }
                }

                // rebuild state fragments for step w+1 (lane-local!)
                if (!(cc == 15 && u == 15)) {
                    float gv = (u < 15) ? gqc[(u + 1) >> 2][(u + 1) & 3] : gqn[0][0];
                    float g0[4], g1[4], g2[4], g3[4];
                    #pragma unroll
                    for (int r = 0; r < 4; ++r) {
                        g0[r] = cur[0][r] * gv; g1[r] = cur[1][r] * gv;
                        g2[r] = cur[2][r] * gv; g3[r] = cur[3][r] * gv;
                    }
                    S0.u[0] = pk2(g0[0], g0[1]); S0.u[1] = pk2(g0[2], g0[3]);
                    S0.u[2] = pk2(g1[0], g1[1]); S0.u[3] = pk2(g1[2], g1[3]);
                    S1.u[0] = pk2(g2[0], g2[1]); S1.u[1] = pk2(g2[2], g2[3]);
                    S1.u[2] = pk2(g3[0], g3[1]); S1.u[3] = pk2(g3[2], g3[3]);
                }
            }
            BAR();  // end of chunk
        };

        #pragma unroll 1
        for (int c2 = 0; c2 < 8; ++c2) {
            run_chunk(Ic<0>{}, 2 * c2);
            run_chunk(Ic<1>{}, 2 * c2 + 1);
        }
    } else if (wid <= 4) {
        // ================= feat stagers (waves 1-4) =================
        // wave handles 8 c-pairs (16 c): cp = (wid-1)*8 + 4*pi + g4, pi=0..1.
        const int cb2 = (wid - 1) * 8;
        const int n = lane & 15;

        auto stage = [&](int buf, int w0) {
            f32x4 ra[2][2][4];  // [pi][row][w-quad], statically indexed
            #pragma unroll
            for (int pi = 0; pi < 2; ++pi) {
                const int cp = cb2 + 4 * pi + g4;
                const float* p0 = fb + (size_t)(2 * cp) * 65536 + n * 256 + w0;
                #pragma unroll
                for (int row = 0; row < 2; ++row)
                    #pragma unroll
                    for (int q = 0; q < 4; ++q)
                        ra[pi][row][q] = *(const f32x4*)(p0 + row * 65536 + 4 * q);
            }
            #pragma unroll
            for (int pi = 0; pi < 2; ++pi) {
                const int cp = cb2 + 4 * pi + g4;
                #pragma unroll
                for (int q = 0; q < 4; ++q)
                    #pragma unroll
                    for (int e = 0; e < 4; ++e) {
                        PkU pk; pk.u = pk2(ra[pi][0][q][e], ra[pi][1][q][e]);
                        *(short2v*)&fs[buf][fsi(4 * q + e, n, 2 * cp)] = pk.s2;
                    }
            }
        };

        stage(0, 0);
        BAR();
        #pragma unroll 1
        for (int cc = 0; cc < 16; ++cc) {
            if (cc < 15) stage((cc + 1) & 1, (cc + 1) * 16);
            BAR();
        }
    } else {
        // ================= out drainers (waves 5-7) =================
        const int wd = wid - 5;                  // 0..2; rows o = wd, wd+3, ...
        const int n = (lane >> 2) & 15, wq = lane & 3;
        float* const ob = outp + ((size_t)(b * 64) * 256 + h0 + n) * 256 + 4 * wq;

        auto drain = [&](int buf, int wpr) {
            for (int o = wd; o < 64; o += 3) {
                short4v d = *(const short4v*)&og[buf][ogi(o, n, 4 * wq)];
                f32x4 o4 = { b2f(d.x), b2f(d.y), b2f(d.z), b2f(d.w) };
                *(f32x4*)(ob + (size_t)o * 65536 + wpr) = o4;
            }
        };

        BAR();
        #pragma unroll 1
        for (int cc = 0; cc < 16; ++cc) {
            if (cc > 0) drain((cc - 1) & 1, (cc - 1) * 16);
            BAR();
        }
        drain(1, 240);  // chunk 15
    }
}

extern "C" void kernel_launch(void* const* d_in, const int* in_sizes, int n_in,
                              void* d_out, int out_size, void* d_ws, size_t ws_size,
                              hipStream_t stream) {
    const float* feat = (const float*)d_in[0];
    const float* conf = (const float*)d_in[1];
    const float* Wi   = (const float*)d_in[2];
    const float* bi   = (const float*)d_in[3];
    const float* Ws   = (const float*)d_in[4];
    const float* bs   = (const float*)d_in[5];
    const float* bias = (const float*)d_in[6];
    float* out = (float*)d_out;
    (void)d_ws; (void)ws_size; (void)in_sizes; (void)n_in; (void)out_size;

    dp_v7_kernel<<<256, 512, 0, stream>>>(feat, conf, Wi, bi, Ws, bs, bias, out);
}

// Round 8
// 204.581 us; speedup vs baseline: 1.7856x; 1.7856x over previous
//
#include <hip/hip_runtime.h>
#include <hip/hip_bf16.h>

// DirectionalPropagation1D fused v8: B=16, C=64, H=256, W=256, N=4096 seqs.
// 256 blocks x 4 waves (rec wave keeps a private SIMD -- v6/v7 showed sharing
// is strictly negative). NEW vs v5: the feat projection (Wi*f + biases) is
// moved OUT of the serial loop: waves 1-2 compute it one 8-w half-chunk ahead
// (global->reg loads, own MFMAs) and write f32 results to LDS in the rec
// wave's C-fragment layout. Rec wave per step: 4 prefetched ds_read_b128
// (acc init = ps) + 8 state MFMAs (permuted-Ws register-state trick, v5) +
// relu/gate/pack. Wave 3 drains og. One lgkm-only barrier per half-chunk.

typedef __attribute__((ext_vector_type(8))) short short8;
typedef __attribute__((ext_vector_type(4))) short short4v;
typedef __attribute__((ext_vector_type(2))) short short2v;
typedef __attribute__((ext_vector_type(4))) float f32x4;

union FragU { unsigned int u[4]; short8 v; };
union PkU { unsigned int u; short2v s2; };

__device__ __forceinline__ unsigned int pk2(float a, float b) {
    unsigned short lo = __bfloat16_as_ushort(__float2bfloat16(a));
    unsigned short hi = __bfloat16_as_ushort(__float2bfloat16(b));
    return (unsigned int)lo | ((unsigned int)hi << 16);
}
__device__ __forceinline__ float b2f(short x) {
    return __uint_as_float(((unsigned int)(unsigned short)x) << 16);
}

// ps: proj staging f32, logical [w8][n16][o64] per buffer. XOR swizzle is the
// SAME pure function on both sides (rule 21): (n&7) term spreads the rec read
// (lanes vary n), (w&7) term spreads the proj write (lanes vary w).
// Flips f32-idx bits 2..4 only -> 16-B (b128) alignment preserved.
__device__ __forceinline__ int psi(int w, int n, int o) {
    return (w * 1024 + n * 64 + o) ^ ((n & 7) << 2) ^ ((w & 7) << 2);
}
// og: out staging bf16 [o64][n16][w16] (16-w granularity), v5's validated ogi.
__device__ __forceinline__ int ogi(int o, int n, int w) {
    return (o * 256 + n * 16 + w) ^ ((((o >> 2) ^ (n >> 2)) & 3) << 2);
}

// LDS-only barrier: global traffic stays in flight across it.
#define BAR() asm volatile("s_waitcnt lgkmcnt(0)\n\ts_barrier" ::: "memory")

template<int V> struct Ic { static constexpr int value = V; };

__global__ __launch_bounds__(256, 1) void dp_v8_kernel(
    const float* __restrict__ feat, const float* __restrict__ conf,
    const float* __restrict__ Wi, const float* __restrict__ bi,
    const float* __restrict__ Ws, const float* __restrict__ bs,
    const float* __restrict__ bias, float* __restrict__ outp)
{
    __shared__ float ps[2][8192];            // 64 KB proj f32, 8-w halves, ping-pong
    __shared__ unsigned short og[2][16384];  // 64 KB out bf16, 16-w chunks, ping-pong

    const int tid = threadIdx.x;
    const int lane = tid & 63;
    const int wid = tid >> 6;                // 0 rec, 1-2 proj, 3 drain
    const int l15 = lane & 15, g4 = lane >> 4;
    const int nb = blockIdx.x;
    const int b = nb >> 4, h0 = (nb & 15) * 16;

    const float* fb = feat + (size_t)b * 64 * 65536 + (size_t)h0 * 256;

    if (wid == 0) {
        // ================= recurrence wave =================
        const float* gb = conf + ((size_t)(b * 256) + h0 + l15) * 256;

        // As: permuted columns K(h,g4,j) = 16*(2h+(d>>1)) + 4g4 + 2(d&1)+e
        // so each lane's D-fragment IS its next-step B-fragment (v5-validated).
        FragU As[4][2];
        #pragma unroll
        for (int t = 0; t < 4; ++t)
            #pragma unroll
            for (int h = 0; h < 2; ++h) {
                const float* ss = Ws + (16 * t + l15) * 64;
                #pragma unroll
                for (int d = 0; d < 4; ++d) {
                    const int c0 = 16 * (2 * h + (d >> 1)) + 4 * g4 + 2 * (d & 1);
                    As[t][h].u[d] = pk2(ss[c0], ss[c0 + 1]);
                }
            }

        f32x4 gqA[4], gqB[4];
        #pragma unroll
        for (int q = 0; q < 4; ++q) gqA[q] = *(const f32x4*)(gb + 4 * q);

        FragU S0, S1;
        #pragma unroll
        for (int d = 0; d < 4; ++d) { S0.u[d] = 0u; S1.u[d] = 0u; }

        float curE[4][4];

        BAR();  // prologue barrier (ps[0] ready)

        auto run_half = [&](auto Hc, auto Qc, int C) {
            constexpr int H = decltype(Hc)::value;   // half index = ps parity
            constexpr int Q = decltype(Qc)::value;   // C&1 = og parity = gate parity
            f32x4 (&gqc)[4] = Q ? gqB : gqA;
            f32x4 (&gqn)[4] = Q ? gqA : gqB;
            f32x4 accP[2][4];
            #pragma unroll
            for (int t = 0; t < 4; ++t)
                accP[0][t] = *(const f32x4*)&ps[H][psi(0, l15, 16 * t + 4 * g4)];
            #pragma unroll
            for (int u = 0; u < 8; ++u) {
                const int wl = H * 8 + u;            // w within 16-chunk C
                if (u < 7) {                          // prefetch next step's proj
                    #pragma unroll
                    for (int t = 0; t < 4; ++t)
                        accP[(u + 1) & 1][t] =
                            *(const f32x4*)&ps[H][psi(u + 1, l15, 16 * t + 4 * g4)];
                }
                if (H == 0 && u == 4 && C < 15) {     // next chunk's gates
                    #pragma unroll
                    for (int q = 0; q < 4; ++q)
                        gqn[q] = *(const f32x4*)(gb + (C + 1) * 16 + 4 * q);
                }

                f32x4 a0 = accP[u & 1][0], a1 = accP[u & 1][1];
                f32x4 a2 = accP[u & 1][2], a3 = accP[u & 1][3];
                a0 = __builtin_amdgcn_mfma_f32_16x16x32_bf16(As[0][0].v, S0.v, a0, 0, 0, 0);
                a1 = __builtin_amdgcn_mfma_f32_16x16x32_bf16(As[1][0].v, S0.v, a1, 0, 0, 0);
                a2 = __builtin_amdgcn_mfma_f32_16x16x32_bf16(As[2][0].v, S0.v, a2, 0, 0, 0);
                a3 = __builtin_amdgcn_mfma_f32_16x16x32_bf16(As[3][0].v, S0.v, a3, 0, 0, 0);
                a0 = __builtin_amdgcn_mfma_f32_16x16x32_bf16(As[0][1].v, S1.v, a0, 0, 0, 0);
                a1 = __builtin_amdgcn_mfma_f32_16x16x32_bf16(As[1][1].v, S1.v, a1, 0, 0, 0);
                a2 = __builtin_amdgcn_mfma_f32_16x16x32_bf16(As[2][1].v, S1.v, a2, 0, 0, 0);
                a3 = __builtin_amdgcn_mfma_f32_16x16x32_bf16(As[3][1].v, S1.v, a3, 0, 0, 0);

                float cur[4][4];
                #pragma unroll
                for (int r = 0; r < 4; ++r) {
                    cur[0][r] = fmaxf(a0[r], 0.f);
                    cur[1][r] = fmaxf(a1[r], 0.f);
                    cur[2][r] = fmaxf(a2[r], 0.f);
                    cur[3][r] = fmaxf(a3[r], 0.f);
                }

                // out staging: pack w-pairs, write b32 on odd wl (v5 pattern).
                if ((wl & 1) == 0) {
                    #pragma unroll
                    for (int t = 0; t < 4; ++t)
                        #pragma unroll
                        for (int r = 0; r < 4; ++r) curE[t][r] = cur[t][r];
                } else {
                    #pragma unroll
                    for (int t = 0; t < 4; ++t)
                        #pragma unroll
                        for (int r = 0; r < 4; ++r) {
                            PkU pk; pk.u = pk2(curE[t][r], cur[t][r]);
                            *(short2v*)&og[Q][ogi(16 * t + 4 * g4 + r, l15, wl - 1)] = pk.s2;
                        }
                }

                // rebuild state fragments for step w+1 (lane-local, v5-validated)
                if (!(C == 15 && wl == 15)) {
                    float gv = (wl < 15) ? gqc[(wl + 1) >> 2][(wl + 1) & 3] : gqn[0][0];
                    float g0[4], g1[4], g2[4], g3[4];
                    #pragma unroll
                    for (int r = 0; r < 4; ++r) {
                        g0[r] = cur[0][r] * gv; g1[r] = cur[1][r] * gv;
                        g2[r] = cur[2][r] * gv; g3[r] = cur[3][r] * gv;
                    }
                    S0.u[0] = pk2(g0[0], g0[1]); S0.u[1] = pk2(g0[2], g0[3]);
                    S0.u[2] = pk2(g1[0], g1[1]); S0.u[3] = pk2(g1[2], g1[3]);
                    S1.u[0] = pk2(g2[0], g2[1]); S1.u[1] = pk2(g2[2], g2[3]);
                    S1.u[2] = pk2(g3[0], g3[1]); S1.u[3] = pk2(g3[2], g3[3]);
                }
            }
            BAR();
        };

        #pragma unroll 1
        for (int c2 = 0; c2 < 8; ++c2) {
            const int C0 = 2 * c2, C1 = 2 * c2 + 1;
            run_half(Ic<0>{}, Ic<0>{}, C0);
            run_half(Ic<1>{}, Ic<0>{}, C0);
            run_half(Ic<0>{}, Ic<1>{}, C1);
            run_half(Ic<1>{}, Ic<1>{}, C1);
        }
    } else if (wid <= 2) {
        // ================= proj waves (1,2): ps = binit + Wi*f =================
        // lanes: cols = (n2, w8) pairs (l15 = n2*8 + w), g4 = k-octet.
        const int nb8 = (wid - 1) * 8;
        const int n2 = l15 >> 3, wq8 = l15 & 7;

        FragU Ai[4][2];
        #pragma unroll
        for (int t = 0; t < 4; ++t)
            #pragma unroll
            for (int h = 0; h < 2; ++h) {
                const float* si = Wi + (16 * t + l15) * 64 + 32 * h + g4 * 8;
                #pragma unroll
                for (int d = 0; d < 4; ++d)
                    Ai[t][h].u[d] = pk2(si[2 * d], si[2 * d + 1]);
            }
        f32x4 binit[4];
        #pragma unroll
        for (int t = 0; t < 4; ++t)
            #pragma unroll
            for (int r = 0; r < 4; ++r) {
                int o = 16 * t + 4 * g4 + r;
                binit[t][r] = bi[o] + bs[o] + bias[o];
            }

        float fr[4][16];   // feat regs for one 8-w half; all indices static
        auto issue_loads = [&](int w0) {
            #pragma unroll
            for (int ng = 0; ng < 4; ++ng) {
                const int nL = nb8 + 2 * ng + n2;
                const float* base = fb + (size_t)nL * 256 + w0 + wq8;
                #pragma unroll
                for (int hh = 0; hh < 2; ++hh)
                    #pragma unroll
                    for (int d = 0; d < 4; ++d) {
                        const int c0 = 32 * hh + 8 * g4 + 2 * d;
                        fr[ng][hh * 8 + 2 * d]     = base[(size_t)c0 * 65536];
                        fr[ng][hh * 8 + 2 * d + 1] = base[(size_t)(c0 + 1) * 65536];
                    }
            }
        };
        auto compute_ps = [&](int buf) {
            #pragma unroll
            for (int ng = 0; ng < 4; ++ng) {
                const int nL = nb8 + 2 * ng + n2;
                FragU B0, B1;
                #pragma unroll
                for (int d = 0; d < 4; ++d) {
                    B0.u[d] = pk2(fr[ng][2 * d],     fr[ng][2 * d + 1]);
                    B1.u[d] = pk2(fr[ng][8 + 2 * d], fr[ng][8 + 2 * d + 1]);
                }
                #pragma unroll
                for (int t = 0; t < 4; ++t) {
                    f32x4 acc = binit[t];
                    acc = __builtin_amdgcn_mfma_f32_16x16x32_bf16(Ai[t][0].v, B0.v, acc, 0, 0, 0);
                    acc = __builtin_amdgcn_mfma_f32_16x16x32_bf16(Ai[t][1].v, B1.v, acc, 0, 0, 0);
                    *(f32x4*)&ps[buf][psi(wq8, nL, 16 * t + 4 * g4)] = acc;
                }
            }
        };

        issue_loads(0);
        compute_ps(0);        // ps[0] = half-chunk 0
        issue_loads(8);       // half-chunk 1 -> regs
        BAR();
        #pragma unroll 1
        for (int hc = 0; hc < 32; ++hc) {
            if (hc < 31) compute_ps((hc + 1) & 1);
            if (hc < 30) issue_loads((hc + 2) * 8);
            BAR();
        }
    } else {
        // ================= out drainer (wave 3) =================
        const int n = (lane >> 2) & 15, wq = lane & 3;
        float* const ob = outp + ((size_t)(b * 64) * 256 + h0 + n) * 256 + 4 * wq;

        auto drain_half = [&](int buf, int wpr, int o0) {
            #pragma unroll 8
            for (int o = o0; o < o0 + 32; ++o) {
                short4v d = *(const short4v*)&og[buf][ogi(o, n, 4 * wq)];
                f32x4 o4 = { b2f(d.x), b2f(d.y), b2f(d.z), b2f(d.w) };
                *(f32x4*)(ob + (size_t)o * 65536 + wpr) = o4;
            }
        };

        BAR();
        #pragma unroll 1
        for (int c2 = 0; c2 < 8; ++c2) {
            const int C0 = 2 * c2;
            if (c2 > 0) drain_half(1, (C0 - 1) * 16, 0);
            BAR();
            if (c2 > 0) drain_half(1, (C0 - 1) * 16, 32);
            BAR();
            drain_half(0, C0 * 16, 0);
            BAR();
            drain_half(0, C0 * 16, 32);
            BAR();
        }
        drain_half(1, 240, 0);   // final chunk C=15
        drain_half(1, 240, 32);
    }
}

extern "C" void kernel_launch(void* const* d_in, const int* in_sizes, int n_in,
                              void* d_out, int out_size, void* d_ws, size_t ws_size,
                              hipStream_t stream) {
    const float* feat = (const float*)d_in[0];
    const float* conf = (const float*)d_in[1];
    const float* Wi   = (const float*)d_in[2];
    const float* bi   = (const float*)d_in[3];
    const float* Ws   = (const float*)d_in[4];
    const float* bs   = (const float*)d_in[5];
    const float* bias = (const float*)d_in[6];
    float* out = (float*)d_out;
    (void)d_ws; (void)ws_size; (void)in_sizes; (void)n_in; (void)out_size;

    dp_v8_kernel<<<256, 256, 0, stream>>>(feat, conf, Wi, bi, Ws, bs, bias, out);
}

// Round 9
// 187.622 us; speedup vs baseline: 1.9470x; 1.0904x over previous
//
#include <hip/hip_runtime.h>
#include <hip/hip_bf16.h>

// DirectionalPropagation1D fused v9: v5 dataflow exactly (256 blocks x 4
// waves: rec / 2 feat stagers / out drainer, per-chunk lgkm-only barriers,
// register-state recurrence via permuted-Ws), but the rec wave is
// DE-UNROLLED: rolled cc/step loops, runtime LDS addressing, gates in a
// 4-slot LDS ring staged 2 chunks ahead by the drainer. Hot code ~1.6 KB
// vs v5's ~22 KB -- tests the I-cache-thrash theory for the 10x idle gap.

typedef __attribute__((ext_vector_type(8))) short short8;
typedef __attribute__((ext_vector_type(4))) short short4v;
typedef __attribute__((ext_vector_type(2))) short short2v;
typedef __attribute__((ext_vector_type(4))) float f32x4;

union FragU { unsigned int u[4]; short8 v; };
union PkU { unsigned int u; short2v s2; };

__device__ __forceinline__ unsigned int pk2(float a, float b) {
    unsigned short lo = __bfloat16_as_ushort(__float2bfloat16(a));
    unsigned short hi = __bfloat16_as_ushort(__float2bfloat16(b));
    return (unsigned int)lo | ((unsigned int)hi << 16);
}
__device__ __forceinline__ float b2f(short x) {
    return __uint_as_float(((unsigned int)(unsigned short)x) << 16);
}

// feat staging [w16][n16][c64] bf16: fsi(w,n,c) = w*1024 + ((n*64+c)^((n&7)<<3))
__device__ __forceinline__ int fsi(int w, int n, int c) {
    return (w * 1024 + n * 64 + c) ^ ((n & 7) << 3);
}
// out staging [o64][n16][w16] bf16 (same pure function both sides; the rec
// wave uses the lane-constant decomposition: swz = ((g4^(n>>2))&3)<<2,
// word = o*256 + n*16 + (w ^ swz), valid since (o>>2)&3 == g4 for o=16t+4g4+r)
__device__ __forceinline__ int ogi(int o, int n, int w) {
    return (o * 256 + n * 16 + w) ^ ((((o >> 2) ^ (n >> 2)) & 3) << 2);
}

// LDS-only barrier: global traffic stays in flight across it.
#define BAR() asm volatile("s_waitcnt lgkmcnt(0)\n\ts_barrier" ::: "memory")

__global__ __launch_bounds__(256, 1) void dp_v9_kernel(
    const float* __restrict__ feat, const float* __restrict__ conf,
    const float* __restrict__ Wi, const float* __restrict__ bi,
    const float* __restrict__ Ws, const float* __restrict__ bs,
    const float* __restrict__ bias, float* __restrict__ outp)
{
    __shared__ unsigned short fs[2][16384];  // 64 KB feat bf16, ping-pong
    __shared__ unsigned short og[2][16384];  // 64 KB out bf16, ping-pong
    __shared__ float gs[4][256];             //  4 KB gates [slot][w16*16+n]

    const int tid = threadIdx.x;
    const int lane = tid & 63;
    const int wid = tid >> 6;
    const int l15 = lane & 15, g4 = lane >> 4;
    const int nb = blockIdx.x;
    const int b = nb >> 4, h0 = (nb & 15) * 16;

    const float* fb = feat + (size_t)b * 64 * 65536 + (size_t)h0 * 256;

    if (wid == 0) {
        // ================= recurrence wave =================
        FragU Ai[4][2], As[4][2];
        #pragma unroll
        for (int t = 0; t < 4; ++t)
            #pragma unroll
            for (int h = 0; h < 2; ++h) {
                const float* si = Wi + (16 * t + l15) * 64 + 32 * h + g4 * 8;
                const float* ss = Ws + (16 * t + l15) * 64;
                #pragma unroll
                for (int d = 0; d < 4; ++d) {
                    Ai[t][h].u[d] = pk2(si[2 * d], si[2 * d + 1]);
                    const int c0 = 16 * (2 * h + (d >> 1)) + 4 * g4 + 2 * (d & 1);
                    As[t][h].u[d] = pk2(ss[c0], ss[c0 + 1]);
                }
            }
        f32x4 binit[4];
        #pragma unroll
        for (int t = 0; t < 4; ++t)
            #pragma unroll
            for (int r = 0; r < 4; ++r) {
                int o = 16 * t + 4 * g4 + r;
                binit[t][r] = bi[o] + bs[o] + bias[o];
            }

        FragU S0, S1;
        #pragma unroll
        for (int d = 0; d < 4; ++d) { S0.u[d] = 0u; S1.u[d] = 0u; }

        // lane-constant address pieces
        const int fo0 = (l15 * 64 + 8 * g4) ^ ((l15 & 7) << 3);
        const int fo1 = (l15 * 64 + 32 + 8 * g4) ^ ((l15 & 7) << 3);
        const int swz = ((g4 ^ (l15 >> 2)) & 3) << 2;
        const int ogl = g4 * 1024 + l15 * 16;

        float curE[4][4];

        auto mstep = [&](const short8& F0, const short8& F1, float (&cur)[4][4]) {
            f32x4 a0 = binit[0], a1 = binit[1], a2 = binit[2], a3 = binit[3];
            a0 = __builtin_amdgcn_mfma_f32_16x16x32_bf16(Ai[0][0].v, F0, a0, 0, 0, 0);
            a1 = __builtin_amdgcn_mfma_f32_16x16x32_bf16(Ai[1][0].v, F0, a1, 0, 0, 0);
            a2 = __builtin_amdgcn_mfma_f32_16x16x32_bf16(Ai[2][0].v, F0, a2, 0, 0, 0);
            a3 = __builtin_amdgcn_mfma_f32_16x16x32_bf16(Ai[3][0].v, F0, a3, 0, 0, 0);
            a0 = __builtin_amdgcn_mfma_f32_16x16x32_bf16(Ai[0][1].v, F1, a0, 0, 0, 0);
            a1 = __builtin_amdgcn_mfma_f32_16x16x32_bf16(Ai[1][1].v, F1, a1, 0, 0, 0);
            a2 = __builtin_amdgcn_mfma_f32_16x16x32_bf16(Ai[2][1].v, F1, a2, 0, 0, 0);
            a3 = __builtin_amdgcn_mfma_f32_16x16x32_bf16(Ai[3][1].v, F1, a3, 0, 0, 0);
            a0 = __builtin_amdgcn_mfma_f32_16x16x32_bf16(As[0][0].v, S0.v, a0, 0, 0, 0);
            a1 = __builtin_amdgcn_mfma_f32_16x16x32_bf16(As[1][0].v, S0.v, a1, 0, 0, 0);
            a2 = __builtin_amdgcn_mfma_f32_16x16x32_bf16(As[2][0].v, S0.v, a2, 0, 0, 0);
            a3 = __builtin_amdgcn_mfma_f32_16x16x32_bf16(As[3][0].v, S0.v, a3, 0, 0, 0);
            a0 = __builtin_amdgcn_mfma_f32_16x16x32_bf16(As[0][1].v, S1.v, a0, 0, 0, 0);
            a1 = __builtin_amdgcn_mfma_f32_16x16x32_bf16(As[1][1].v, S1.v, a1, 0, 0, 0);
            a2 = __builtin_amdgcn_mfma_f32_16x16x32_bf16(As[2][1].v, S1.v, a2, 0, 0, 0);
            a3 = __builtin_amdgcn_mfma_f32_16x16x32_bf16(As[3][1].v, S1.v, a3, 0, 0, 0);
            #pragma unroll
            for (int r = 0; r < 4; ++r) {
                cur[0][r] = fmaxf(a0[r], 0.f);
                cur[1][r] = fmaxf(a1[r], 0.f);
                cur[2][r] = fmaxf(a2[r], 0.f);
                cur[3][r] = fmaxf(a3[r], 0.f);
            }
        };
        auto rebuild = [&](const float (&cur)[4][4], float gv) {
            float g0[4], g1[4], g2[4], g3[4];
            #pragma unroll
            for (int r = 0; r < 4; ++r) {
                g0[r] = cur[0][r] * gv; g1[r] = cur[1][r] * gv;
                g2[r] = cur[2][r] * gv; g3[r] = cur[3][r] * gv;
            }
            S0.u[0] = pk2(g0[0], g0[1]); S0.u[1] = pk2(g0[2], g0[3]);
            S0.u[2] = pk2(g1[0], g1[1]); S0.u[3] = pk2(g1[2], g1[3]);
            S1.u[0] = pk2(g2[0], g2[1]); S1.u[1] = pk2(g2[2], g2[3]);
            S1.u[2] = pk2(g3[0], g3[1]); S1.u[3] = pk2(g3[2], g3[3]);
        };

        BAR();  // prologue barrier

        #pragma unroll 1
        for (int cc = 0; cc < 16; ++cc) {
            const unsigned short* fsb = fs[cc & 1];
            unsigned short* ogb = og[cc & 1];
            const float* gsc = gs[cc & 3];
            const float* gsn = gs[(cc + 1) & 3];

            short8 Fn0 = *(const short8*)&fsb[fo0];
            short8 Fn1 = *(const short8*)&fsb[fo1];

            #pragma unroll 1
            for (int up = 0; up < 8; ++up) {
                // ---- even step u = 2*up (never the global last step) ----
                {
                    const int u = 2 * up;
                    short8 F0 = Fn0, F1 = Fn1;
                    Fn0 = *(const short8*)&fsb[(u + 1) * 1024 + fo0];
                    Fn1 = *(const short8*)&fsb[(u + 1) * 1024 + fo1];
                    float gvn = gsc[(u + 1) * 16 + l15];
                    float cur[4][4];
                    mstep(F0, F1, cur);
                    #pragma unroll
                    for (int t = 0; t < 4; ++t)
                        #pragma unroll
                        for (int r = 0; r < 4; ++r) curE[t][r] = cur[t][r];
                    rebuild(cur, gvn);
                }
                // ---- odd step u = 2*up+1 ----
                {
                    const int u = 2 * up + 1;
                    short8 F0 = Fn0, F1 = Fn1;
                    if (up < 7) {
                        Fn0 = *(const short8*)&fsb[(u + 1) * 1024 + fo0];
                        Fn1 = *(const short8*)&fsb[(u + 1) * 1024 + fo1];
                    }
                    float gvn = (up < 7) ? gsc[(u + 1) * 16 + l15] : gsn[l15];
                    float cur[4][4];
                    mstep(F0, F1, cur);
                    // og writes: word = ogl + ((u-1)^swz) + t*4096 + r*256
                    unsigned short* opb = ogb + ogl + ((u - 1) ^ swz);
                    #pragma unroll
                    for (int t = 0; t < 4; ++t)
                        #pragma unroll
                        for (int r = 0; r < 4; ++r) {
                            PkU pk; pk.u = pk2(curE[t][r], cur[t][r]);
                            *(short2v*)&opb[t * 4096 + r * 256] = pk.s2;
                        }
                    if (!(cc == 15 && up == 7)) rebuild(cur, gvn);
                }
            }
            BAR();
        }
    } else if (wid <= 2) {
        // ================= feat stagers (waves 1,2) -- v5 verbatim =========
        const int cb2 = (wid - 1) * 16;
        const int n = lane & 15;

        auto stage = [&](int buf, int w0) {
            f32x4 ra[4][2][4];
            #pragma unroll
            for (int pi = 0; pi < 4; ++pi) {
                const int cp = cb2 + 4 * pi + g4;
                const float* p0 = fb + (size_t)(2 * cp) * 65536 + n * 256 + w0;
                #pragma unroll
                for (int row = 0; row < 2; ++row)
                    #pragma unroll
                    for (int q = 0; q < 4; ++q)
                        ra[pi][row][q] = *(const f32x4*)(p0 + row * 65536 + 4 * q);
            }
            #pragma unroll
            for (int pi = 0; pi < 4; ++pi) {
                const int cp = cb2 + 4 * pi + g4;
                #pragma unroll
                for (int q = 0; q < 4; ++q)
                    #pragma unroll
                    for (int e = 0; e < 4; ++e) {
                        PkU pk; pk.u = pk2(ra[pi][0][q][e], ra[pi][1][q][e]);
                        *(short2v*)&fs[buf][fsi(4 * q + e, n, 2 * cp)] = pk.s2;
                    }
            }
        };

        stage(0, 0);
        BAR();
        #pragma unroll 1
        for (int cc = 0; cc < 16; ++cc) {
            if (cc < 15) stage((cc + 1) & 1, (cc + 1) * 16);
            BAR();
        }
    } else {
        // ================= out drainer (wave 3) + gate stager =============
        const int n = (lane >> 2) & 15, wq = lane & 3;
        float* const ob = outp + ((size_t)(b * 64) * 256 + h0 + n) * 256 + 4 * wq;
        const float* const gbd = conf + ((size_t)(b * 256) + h0 + n) * 256;

        auto drain = [&](int buf, int wpr) {
            #pragma unroll 8
            for (int o = 0; o < 64; ++o) {
                short4v d = *(const short4v*)&og[buf][ogi(o, n, 4 * wq)];
                f32x4 o4 = { b2f(d.x), b2f(d.y), b2f(d.z), b2f(d.w) };
                *(f32x4*)(ob + (size_t)o * 65536 + wpr) = o4;
            }
        };
        auto stage_gs = [&](int k) {   // gates for chunk k -> slot k&3
            f32x4 v = *(const f32x4*)(gbd + 16 * k + 4 * wq);
            float* gd = gs[k & 3];
            #pragma unroll
            for (int e = 0; e < 4; ++e) gd[(4 * wq + e) * 16 + n] = v[e];
        };

        stage_gs(0);
        stage_gs(1);
        BAR();
        #pragma unroll 1
        for (int cc = 0; cc < 16; ++cc) {
            if (cc > 0) drain((cc - 1) & 1, (cc - 1) * 16);
            if (cc < 14) stage_gs(cc + 2);
            BAR();
        }
        drain(1, 240);  // final chunk
    }
}

extern "C" void kernel_launch(void* const* d_in, const int* in_sizes, int n_in,
                              void* d_out, int out_size, void* d_ws, size_t ws_size,
                              hipStream_t stream) {
    const float* feat = (const float*)d_in[0];
    const float* conf = (const float*)d_in[1];
    const float* Wi   = (const float*)d_in[2];
    const float* bi   = (const float*)d_in[3];
    const float* Ws   = (const float*)d_in[4];
    const float* bs   = (const float*)d_in[5];
    const float* bias = (const float*)d_in[6];
    float* out = (float*)d_out;
    (void)d_ws; (void)ws_size; (void)in_sizes; (void)n_in; (void)out_size;

    dp_v9_kernel<<<256, 256, 0, stream>>>(feat, conf, Wi, bi, Ws, bs, bias, out);
}